// Round 14
// baseline (97.961 us; speedup 1.0000x reference)
//
#include <hip/hip_runtime.h>

#define HH 256
#define WW 128
#define DD 256
#define HID 8
#define G 16              // samples per block
#define NP2 (G / 2)       // 8 sample-pairs
#define IMG (HH * WW)

typedef float v4f __attribute__((ext_vector_type(4)));

__device__ __forceinline__ void pl32swap(float& a, float& b) {
    asm("v_permlane32_swap_b32 %0, %1" : "+v"(a), "+v"(b));
}
template <int CTRL>
__device__ __forceinline__ float dpp_get(float v) {
    return __int_as_float(__builtin_amdgcn_update_dpp(
        0, __float_as_int(v), CTRL, 0xf, 0xf, true));
}
#define DPP_QUAD_XOR1 177     // quad_perm [1,0,3,2]
#define DPP_QUAD_XOR2 78      // quad_perm [2,3,0,1]

__global__ __launch_bounds__(512, 4)
void lca_kernel(const float* __restrict__ x, const float* __restrict__ We,
                const float* __restrict__ be, const float* __restrict__ Wd,
                const float* __restrict__ bd, float* __restrict__ out) {
    // Zp[buf][s][w][p*8 + par*4 + k] : per-wave partials (rows 2w,2w+1), h = 2k+par
    __shared__ float Zp[2][2][8][64];
    // Zf[buf][s][p*8 + h] : final z with bias
    __shared__ float Zf[2][2][64];

    const int bid = blockIdx.x;
    const int ph  = bid & 15;               // stripe (16 rows)
    const int sg  = bid >> 4;               // sample group
    const int tid = threadIdx.x;
    const int w   = tid >> 6;               // wave index
    const int l   = tid & 63;
    const int p   = (tid >> 2) & 7;         // patch owned by this thread's slot
    const int r   = tid >> 5;               // row within stripe (0..15)
    const int d0  = r * 16 + 4 * (tid & 3); // patch-element base of this thread's 4
    const int pg  = ph * 8 + p;             // global patch id
    const int goff = tid * 4;               // contiguous stripe offset

    // ---- encode weights: this thread's 4 elements, all 8 hidden ----
    v4f we4[HID];
#pragma unroll
    for (int h = 0; h < HID; ++h)
        we4[h] = *(const v4f*)(We + ((size_t)(pg * HID + h)) * DD + d0);

    // ---- decode weights: same 4 elements ----
    v4f wd4[4][2];
#pragma unroll
    for (int c = 0; c < 4; ++c) {
        const v4f* wp = (const v4f*)(Wd + ((size_t)(pg * DD + d0 + c)) * HID);
        wd4[c][0] = wp[0];
        wd4[c][1] = wp[1];
    }
    v4f bdv = *(const v4f*)(bd + pg * DD + d0);

    // finalize-task bias (tid<128): task (s = tid>>6, p = (tid>>3)&7, h = tid&7)
    float bef = 0.f;
    if (tid < 128)
        bef = be[(ph * 8 + ((tid >> 3) & 7)) * HID + (tid & 7)];

    const float* xs = x   + (size_t)(sg * G) * IMG + ph * 2048;
    float*       os = out + (size_t)(sg * G) * IMG + ph * 2048;

    const bool writer = (l & 3) == 0;
    const int  par    = l >> 5;

    auto encode = [&](const v4f& xv, int buf, int ss) {
        float pt[HID];
#pragma unroll
        for (int h = 0; h < HID; ++h)
            pt[h] = fmaf(we4[h].x, xv.x,
                    fmaf(we4[h].y, xv.y,
                    fmaf(we4[h].z, xv.z, we4[h].w * xv.w)));
        // quad reduce: sums the 4 col-groups = full 16-col patch row
#pragma unroll
        for (int h = 0; h < HID; ++h) {
            pt[h] += dpp_get<DPP_QUAD_XOR1>(pt[h]);
            pt[h] += dpp_get<DPP_QUAD_XOR2>(pt[h]);
        }
        // row-pair reduce via permlane32_swap; lane<32 keeps even h, lane>=32 odd h
        pl32swap(pt[0], pt[1]); float s0 = pt[0] + pt[1];
        pl32swap(pt[2], pt[3]); float s1 = pt[2] + pt[3];
        pl32swap(pt[4], pt[5]); float s2 = pt[4] + pt[5];
        pl32swap(pt[6], pt[7]); float s3 = pt[6] + pt[7];
        if (writer) {   // 16 lanes: p*8+par*4, covers words 0..63 once (2-way, free)
            v4f v = {s0, s1, s2, s3};
            *(v4f*)&Zp[buf][ss][w][p * 8 + par * 4] = v;
        }
    };

    auto finalize = [&](int j) {   // Zp[j&1] -> Zf[j&1] (waves 0-1 only)
        if (tid < 128) {
            const int s  = tid >> 6;
            const int pp = (tid >> 3) & 7;
            const int hh = tid & 7;
            const float* zp0 = &Zp[j & 1][s][0][pp * 8 + (hh & 1) * 4 + (hh >> 1)];
            float acc = bef;
#pragma unroll
            for (int w8 = 0; w8 < 8; ++w8) acc += zp0[w8 * 64];
            Zf[j & 1][s][pp * 8 + hh] = acc;
        }
    };

    auto decode = [&](int j) {     // Zf[j&1] -> out (same path as R13)
#pragma unroll
        for (int ss = 0; ss < 2; ++ss) {
            const float* zp = &Zf[j & 1][ss][p * 8];
            v4f z0 = *(const v4f*)zp;
            v4f z1 = *(const v4f*)(zp + 4);
            v4f o;
#pragma unroll
            for (int c = 0; c < 4; ++c) {
                float acc = bdv[c];
#pragma unroll
                for (int h = 0; h < 4; ++h) acc = fmaf(wd4[c][0][h], z0[h], acc);
#pragma unroll
                for (int h = 0; h < 4; ++h) acc = fmaf(wd4[c][1][h], z1[h], acc);
                o[c] = __builtin_amdgcn_rcpf(1.0f + __expf(-acc));
            }
            __builtin_nontemporal_store(
                o, (v4f*)(os + (size_t)(2 * j + ss) * IMG + goff));
        }
    };

    // prologue: load pair 0 directly into registers (no staging)
    v4f xv0 = *(const v4f*)(xs + goff);
    v4f xv1 = *(const v4f*)(xs + IMG + goff);

    // 3-deep pipeline: encode(q) || finalize(q-1) || decode(q-2); 1 barrier/pair
#pragma unroll 1
    for (int q = 0; q < NP2; ++q) {
        __syncthreads();
        v4f xr0, xr1;
        if (q + 1 < NP2) {
            xr0 = *(const v4f*)(xs + (size_t)(2 * q + 2) * IMG + goff);
            xr1 = *(const v4f*)(xs + (size_t)(2 * q + 3) * IMG + goff);
        }
        if (q >= 2) decode(q - 2);
        encode(xv0, q & 1, 0);
        encode(xv1, q & 1, 1);
        if (q >= 1) finalize(q - 1);
        xv0 = xr0; xv1 = xr1;
    }

    // epilogue: drain the pipeline
    __syncthreads();
    finalize(NP2 - 1);
    decode(NP2 - 2);
    __syncthreads();
    decode(NP2 - 1);
}

extern "C" void kernel_launch(void* const* d_in, const int* in_sizes, int n_in,
                              void* d_out, int out_size, void* d_ws, size_t ws_size,
                              hipStream_t stream) {
    const float* x  = (const float*)d_in[0];
    const float* We = (const float*)d_in[1];
    const float* be = (const float*)d_in[2];
    const float* Wd = (const float*)d_in[3];
    const float* bd = (const float*)d_in[4];
    float* out = (float*)d_out;

    const int n_total = in_sizes[0] / IMG;          // 2048
    const int grid    = 16 * (n_total / G);         // 2048 blocks
    lca_kernel<<<dim3(grid), dim3(512), 0, stream>>>(x, We, be, Wd, bd, out);
}